// Round 6
// baseline (486.894 us; speedup 1.0000x reference)
//
#include <hip/hip_runtime.h>
#include <hip/hip_bf16.h>

typedef unsigned short u16;
typedef short short8 __attribute__((ext_vector_type(8)));
typedef float f32x4 __attribute__((ext_vector_type(4)));

#define N_EMBD   1024
#define N_HEADS  16
#define HEAD_DIM 64
#define PRIV     48
#define SEQ_T    2048
#define BATCH    4
#define M_ROWS   (BATCH*SEQ_T)   // 8192
#define PNS      2688            // [share 16 | q 768 | k 768 | v 1024] = 2576 -> 21*128
#define NTILES   (SEQ_T/64)      // 32

#if __has_builtin(__builtin_amdgcn_exp2f)
#define EXP2(x) __builtin_amdgcn_exp2f(x)
#else
#define EXP2(x) exp2f(x)
#endif

#if __has_builtin(__builtin_amdgcn_global_load_lds)
#define HAVE_GLL 1
#else
#define HAVE_GLL 0
#endif

__device__ __forceinline__ u16 f2bf(float f) {
  __hip_bfloat16 h = __float2bfloat16(f);
  return *reinterpret_cast<u16*>(&h);
}
__device__ __forceinline__ float bf2f(u16 s) {
  __hip_bfloat16 h;
  *reinterpret_cast<u16*>(&h) = s;
  return __bfloat162float(h);
}
__device__ __forceinline__ float loadv(const void* p, size_t i, int isf32) {
  return isf32 ? ((const float*)p)[i] : bf2f(((const u16*)p)[i]);
}
__device__ __forceinline__ u16 truncbf(float f) {
  unsigned u = __builtin_bit_cast(unsigned, f);
  return (u16)(u >> 16);
}
#if HAVE_GLL
__device__ __forceinline__ void gload_lds16(const u16* g, u16* l) {
  __builtin_amdgcn_global_load_lds(
      (const __attribute__((address_space(1))) void*)g,
      (__attribute__((address_space(3))) void*)l, 16, 0, 0);
}
#endif

// ---------------------------------------------------------------------------
// Dtype detector (1 = f32 inputs).
// ---------------------------------------------------------------------------
__global__ __launch_bounds__(256) void detect_kernel(const u16* __restrict__ x,
                                                     int* __restrict__ flag) {
  __shared__ int cnt;
  if (threadIdx.x == 0) cnt = 0;
  __syncthreads();
  u16 v = x[2 * threadIdx.x];
  int e = (v >> 7) & 0xFF;
  int junk = (e >= 0xC0 || (e != 0 && e <= 0x30)) ? 1 : 0;
  if (junk) atomicAdd(&cnt, 1);
  __syncthreads();
  if (threadIdx.x == 0) *flag = (cnt > 16) ? 1 : 0;
}

// ---------------------------------------------------------------------------
// Coalesced transposing pack: dst[(rowOff+n)*1024 + k] = src[k][n] via 64x64
// LDS tiles (stride 65). blockIdx.z selects which source matrix.
// ---------------------------------------------------------------------------
__global__ __launch_bounds__(256) void pack_t_kernel(
    const void* __restrict__ Wsh, const void* __restrict__ Wq,
    const void* __restrict__ Wk,  const void* __restrict__ Wv,
    const void* __restrict__ Wo,
    u16* __restrict__ Wcat, u16* __restrict__ Woc,
    const int* __restrict__ flagp)
{
  const int f = *flagp;
  const void* src; u16* dst; int N, rowOff;
  switch (blockIdx.z) {
    case 0: src = Wsh; dst = Wcat; N = 16;   rowOff = 0;    break;
    case 1: src = Wq;  dst = Wcat; N = 768;  rowOff = 16;   break;
    case 2: src = Wk;  dst = Wcat; N = 768;  rowOff = 784;  break;
    case 3: src = Wv;  dst = Wcat; N = 1024; rowOff = 1552; break;
    default:src = Wo;  dst = Woc;  N = 1024; rowOff = 0;    break;
  }
  const int n0 = blockIdx.x * 64;
  if (n0 >= N) return;
  const int k0 = blockIdx.y * 64;
  __shared__ u16 t[64][65];
  const int tx = threadIdx.x & 63, ty = threadIdx.x >> 6;
#pragma unroll
  for (int rr = 0; rr < 16; rr++) {
    int k = k0 + ty * 16 + rr;
    int n = n0 + tx;
    float v = (n < N) ? loadv(src, (size_t)k * N + n, f) : 0.f;
    t[ty * 16 + rr][tx] = f2bf(v);
  }
  __syncthreads();
#pragma unroll
  for (int rr = 0; rr < 16; rr++) {
    int n = ty * 16 + rr;
    if (n0 + n < N)
      dst[(size_t)(rowOff + n0 + n) * 1024 + k0 + tx] = t[tx][n];
  }
}

// ---------------------------------------------------------------------------
// Zero-pad Wcat rows 2576..2688 and pack biases.
// ---------------------------------------------------------------------------
__global__ __launch_bounds__(256) void pad_bias_kernel(
    const void* __restrict__ bsh, const void* __restrict__ bq,
    const void* __restrict__ bk,  const void* __restrict__ bv,
    const void* __restrict__ bo,
    u16* __restrict__ Wcat, u16* __restrict__ bcat, u16* __restrict__ boc,
    const int* __restrict__ flagp)
{
  const int f = *flagp;
  const int padN = (PNS - 2576) * 1024;
  for (int i = blockIdx.x * 256 + threadIdx.x; i < padN; i += gridDim.x * 256)
    Wcat[(size_t)2576 * 1024 + i] = 0;
  if (blockIdx.x == 0) {
    for (int c = threadIdx.x; c < PNS; c += 256) {
      float v = 0.f;
      if (c < 16)        v = loadv(bsh, c, f);
      else if (c < 784)  v = loadv(bq, c - 16, f);
      else if (c < 1552) v = loadv(bk, c - 784, f);
      else if (c < 2576) v = loadv(bv, c - 1552, f);
      bcat[c] = f2bf(v);
    }
    for (int c = threadIdx.x; c < N_EMBD; c += 256)
      boc[c] = f2bf(loadv(bo, c, f));
  }
}

// ---------------------------------------------------------------------------
// BF16 GEMM, register-prefetch double-buffered pipeline.
// C(MxN) = A(MxK) @ Bt(NxK)^T + bias. 128x128 tile, BK=32, 256 thr.
// Per iter: issue next tile's buffer_loads -> regs, MFMA from LDS[cur],
// ds_write regs -> LDS[nxt], ONE barrier. No vmcnt(0)-at-barrier drain.
// XOR chunk swizzle: phys chunk = logical ^ (m&3) ^ ((m>>2)&3) -> <=2-way
// (free) conflicts on both ds_write_b128 and ds_read_b128.
// XCD-aware 1-D grid swizzle (requires M = 8192).
// Template AF32: separate instantiation for f32 A input (keeps hot-path VGPRs
// low); wrong-variant launch exits on the flag.
// ---------------------------------------------------------------------------
template <bool AF32>
__global__ __launch_bounds__(256, 3) void gemm_bias_kernel(
    const void* __restrict__ A, int lda,
    const u16* __restrict__ Bt,     // [N][K] row-major
    const u16* __restrict__ bias,
    void* __restrict__ C, int ldc, int K,
    const int* __restrict__ flagp, int a_dyn, int c_dyn)
{
  const int isf = *flagp;
  if (AF32 != (a_dyn != 0 && isf != 0)) return;   // uniform exit, wrong variant
  const bool cf32 = (c_dyn != 0) && (isf != 0);

  __shared__ __align__(16) u16 As[2][128 * 32];
  __shared__ __align__(16) u16 Bs[2][128 * 32];
  const int tid  = threadIdx.x;
  const int lane = tid & 63;
  const int w    = tid >> 6;
  const int quad = lane >> 4;
  const int l16  = lane & 15;

  // XCD-aware block swizzle (bid -> XCD assumed bid % 8)
  const int bid = blockIdx.x;
  const int xcd = bid & 7;
  const int s   = bid >> 3;
  const int mb  = xcd * 8 + (s & 7);
  const int nb  = s >> 3;
  const int m0  = mb * 128;
  const int n0  = nb * 128;
  const int wm  = (w >> 1) * 64;
  const int wn  = (w & 1) * 64;

  // per-thread staging slots: round i covers element-chunk c = tid + i*256
  int gOff[2], lOff[2];
#pragma unroll
  for (int i = 0; i < 2; i++) {
    int c = tid + i * 256;
    int m = c >> 2;            // row in tile (0..127)
    int l = c & 3;             // logical k-chunk
    int p = l ^ (m & 3) ^ ((m >> 2) & 3);
    gOff[i] = m * 32 + l * 8;  // needs (size_t)(m0+m)*lda split; store row & col
    lOff[i] = m * 32 + p * 8;
  }
  // split gOff into row/col for 64-bit addressing
  int rowS[2], colS[2];
#pragma unroll
  for (int i = 0; i < 2; i++) { rowS[i] = gOff[i] >> 5; colS[i] = (gOff[i] & 31); }

  uint4 ra[2], rb[2];
  float4 fa[2][2];  // only used by AF32 instantiation

  const u16* A16 = (const u16*)A;
  const float* A32 = (const float*)A;

#define FETCH(k0)                                                              \
  {                                                                            \
    _Pragma("unroll") for (int i = 0; i < 2; i++) {                            \
      if (AF32) {                                                              \
        const float* src = A32 + (size_t)(m0 + rowS[i]) * lda + (k0) + colS[i];\
        fa[i][0] = *(const float4*)src;                                        \
        fa[i][1] = *(const float4*)(src + 4);                                  \
      } else {                                                                 \
        ra[i] = *(const uint4*)(A16 + (size_t)(m0 + rowS[i]) * lda + (k0) + colS[i]); \
      }                                                                        \
      rb[i] = *(const uint4*)(Bt + (size_t)(n0 + rowS[i]) * K + (k0) + colS[i]);\
    }                                                                          \
  }

#define STORE_LDS(buf)                                                         \
  {                                                                            \
    _Pragma("unroll") for (int i = 0; i < 2; i++) {                            \
      if (AF32) {                                                              \
        u16 t[8];                                                              \
        t[0] = f2bf(fa[i][0].x); t[1] = f2bf(fa[i][0].y);                      \
        t[2] = f2bf(fa[i][0].z); t[3] = f2bf(fa[i][0].w);                      \
        t[4] = f2bf(fa[i][1].x); t[5] = f2bf(fa[i][1].y);                      \
        t[6] = f2bf(fa[i][1].z); t[7] = f2bf(fa[i][1].w);                      \
        *(uint4*)&As[buf][lOff[i]] = *(const uint4*)t;                         \
      } else {                                                                 \
        *(uint4*)&As[buf][lOff[i]] = ra[i];                                    \
      }                                                                        \
      *(uint4*)&Bs[buf][lOff[i]] = rb[i];                                      \
    }                                                                          \
  }

  f32x4 acc[4][4];
#pragma unroll
  for (int i = 0; i < 4; i++)
#pragma unroll
    for (int j = 0; j < 4; j++) acc[i][j] = (f32x4){0.f, 0.f, 0.f, 0.f};

  // frag-read swizzle offset (uniform across mt/nt: row&3==l16&3 etc.)
  const int swr = (quad ^ (l16 & 3) ^ ((l16 >> 2) & 3)) * 8;

  // prologue: tile 0
  FETCH(0);
  STORE_LDS(0);
  __syncthreads();

  const int NIT = K / 32;
  for (int kt = 0; kt < NIT; kt++) {
    const int cur = kt & 1;
    if (kt + 1 < NIT) FETCH((kt + 1) * 32);

    short8 af[4], bfr[4];
#pragma unroll
    for (int mt = 0; mt < 4; mt++)
      af[mt] = *(const short8*)&As[cur][(wm + mt * 16 + l16) * 32 + swr];
#pragma unroll
    for (int nt = 0; nt < 4; nt++)
      bfr[nt] = *(const short8*)&Bs[cur][(wn + nt * 16 + l16) * 32 + swr];
#pragma unroll
    for (int mt = 0; mt < 4; mt++)
#pragma unroll
      for (int nt = 0; nt < 4; nt++)
        acc[mt][nt] = __builtin_amdgcn_mfma_f32_16x16x32_bf16(af[mt], bfr[nt], acc[mt][nt], 0, 0, 0);

    if (kt + 1 < NIT) {
      STORE_LDS(1 - cur);
      __syncthreads();
    }
  }
#undef FETCH
#undef STORE_LDS

  // ---- epilogue: C/D layout col=lane&15, row=quad*4+reg ----
#pragma unroll
  for (int nt = 0; nt < 4; nt++) {
    int col  = n0 + wn + nt * 16 + l16;
    float bv = bf2f(bias[col]);
#pragma unroll
    for (int mt = 0; mt < 4; mt++) {
#pragma unroll
      for (int r = 0; r < 4; r++) {
        int row   = m0 + wm + mt * 16 + quad * 4 + r;
        float val = acc[mt][nt][r] + bv;
        if (cf32) ((float*)C)[(size_t)row * ldc + col] = val;
        else      ((u16*)C)[(size_t)row * ldc + col]   = f2bf(val);
      }
    }
  }
}

// ---------------------------------------------------------------------------
// Causal flash attention, balanced-pair version (unchanged from R5).
// ---------------------------------------------------------------------------
__global__ __launch_bounds__(256, 4) void attn_kernel(
    const u16* __restrict__ P, u16* __restrict__ Y)
{
  const int bh  = blockIdx.x;
  const int b   = bh >> 4, h = bh & 15;
  const int p   = blockIdx.y;           // 0..15
  const int qtA = p, qtB = NTILES - 1 - p;
  const int tid = threadIdx.x;
  const int w   = tid >> 6;
  const int lane = tid & 63;
  const int quad = lane >> 4, l16 = lane & 15;
  const size_t rowb = (size_t)b * SEQ_T;
  const int qcol = 16 + h * PRIV;
  const int kcol = 784 + h * PRIV;
  const int vcol = 1552 + h * HEAD_DIM;

  __shared__ __align__(16) u16 Ks[64 * 64];        // swizzled [j][chunk^j]
  __shared__ __align__(16) u16 Vs[64 * 68];        // [d][j], stride 68
  __shared__ __align__(16) u16 Ps[4][2][16 * 68];  // [wave][chain]

  const float csc = 0.18033688011112042f;  // (1/8)*log2(e)
  const int d0  = quad * 8;
  const int cq0 = (d0 < 16) ? d0 : (qcol + d0 - 16);
  const int ck0 = (d0 < 16) ? d0 : (kcol + d0 - 16);
  const int iA = qtA * 64 + w * 16, iB = qtB * 64 + w * 16;
  const u16* qrowA = P + (rowb + iA + l16) * PNS;
  const u16* qrowB = P + (rowb + iB + l16) * PNS;
  short8 qaA0 = *(const short8*)&qrowA[cq0];
  short8 qaA1 = *(const short8*)&qrowA[qcol + 16 + d0];
  short8 qaB0 = *(const short8*)&qrowB[cq0];
  short8 qaB1 = *(const short8*)&qrowB[qcol + 16 + d0];
#pragma unroll
  for (int e = 0; e < 8; e++) {
    qaA0[e] = (short)f2bf(bf2f((u16)qaA0[e]) * csc);
    qaA1[e] = (short)f2bf(bf2f((u16)qaA1[e]) * csc);
    qaB0[e] = (short)f2bf(bf2f((u16)qaB0[e]) * csc);
    qaB1[e] = (short)f2bf(bf2f((u16)qaB1[e]) * csc);
  }
  short8 ones;
#pragma unroll
  for (int e = 0; e < 8; e++) ones[e] = (short)0x3F80;

  f32x4 accyA[4], accyB[4], acclA, acclB;
#pragma unroll
  for (int g = 0; g < 4; g++) {
    accyA[g] = (f32x4){0.f, 0.f, 0.f, 0.f};
    accyB[g] = (f32x4){0.f, 0.f, 0.f, 0.f};
  }
  acclA = (f32x4){0.f, 0.f, 0.f, 0.f};
  acclB = (f32x4){0.f, 0.f, 0.f, 0.f};

  const int nkt = qtB + 1;
  for (int kt = 0; kt < nkt; kt++) {
    const int k0 = kt * 64;
    __syncthreads();  // previous K/V tiles fully consumed

    // ---- stage K tile via global_load_lds, XOR swizzle ----
#pragma unroll
    for (int i2 = 0; i2 < 2; i2++) {
      int c   = tid + i2 * 256;
      int row = c >> 3;
      int qc  = c & 7;
      int dg  = (qc ^ (row & 7)) * 8;
      int col = (dg < 16) ? dg : (kcol + dg - 16);
      const u16* gp = &P[(rowb + k0 + row) * PNS + col];
#if HAVE_GLL
      gload_lds16(gp, &Ks[c * 8]);
#else
      *(uint4*)&Ks[c * 8] = *(const uint4*)gp;
#endif
    }
    // ---- stage V transposed ----
#pragma unroll
    for (int i2 = 0; i2 < 2; i2++) {
      int c  = tid + i2 * 256;
      int j  = c & 63;
      int dc = (c >> 6) * 8;
      uint4 v = *(const uint4*)&P[(rowb + k0 + j) * PNS + vcol + dc];
      const u16* pv = (const u16*)&v;
#pragma unroll
      for (int e = 0; e < 8; e++) Vs[(dc + e) * 68 + j] = pv[e];
    }
    __syncthreads();

    const bool doA = (kt <= qtA);

    float svA[4][4], svB[4][4];
#pragma unroll
    for (int g = 0; g < 4; g++) {
      int j = g * 16 + l16;
      short8 kb0 = *(const short8*)&Ks[j * 64 + ((quad    ) ^ (j & 7)) * 8];
      short8 kb1 = *(const short8*)&Ks[j * 64 + ((quad + 4) ^ (j & 7)) * 8];
      f32x4 sB = (f32x4){0.f, 0.f, 0.f, 0.f};
      sB = __builtin_amdgcn_mfma_f32_16x16x32_bf16(qaB0, kb0, sB, 0, 0, 0);
      sB = __builtin_amdgcn_mfma_f32_16x16x32_bf16(qaB1, kb1, sB, 0, 0, 0);
#pragma unroll
      for (int r = 0; r < 4; r++) svB[g][r] = sB[r];
      if (doA) {
        f32x4 sA = (f32x4){0.f, 0.f, 0.f, 0.f};
        sA = __builtin_amdgcn_mfma_f32_16x16x32_bf16(qaA0, kb0, sA, 0, 0, 0);
        sA = __builtin_amdgcn_mfma_f32_16x16x32_bf16(qaA1, kb1, sA, 0, 0, 0);
#pragma unroll
        for (int r = 0; r < 4; r++) svA[g][r] = sA[r];
      }
    }
    if (kt == qtA && doA) {
#pragma unroll
      for (int g = 0; g < 4; g++)
#pragma unroll
        for (int r = 0; r < 4; r++) {
          int gi = iA + quad * 4 + r;
          int gj = k0 + g * 16 + l16;
          if (gj > gi) svA[g][r] = -__builtin_inff();
        }
    }
    if (kt == qtB) {
#pragma unroll
      for (int g = 0; g < 4; g++)
#pragma unroll
        for (int r = 0; r < 4; r++) {
          int gi = iB + quad * 4 + r;
          int gj = k0 + g * 16 + l16;
          if (gj > gi) svB[g][r] = -__builtin_inff();
        }
    }

    if (doA) {
#pragma unroll
      for (int g = 0; g < 4; g++)
#pragma unroll
        for (int r = 0; r < 4; r++)
          Ps[w][0][(quad * 4 + r) * 68 + g * 16 + l16] = truncbf(EXP2(svA[g][r]));
    }
#pragma unroll
    for (int g = 0; g < 4; g++)
#pragma unroll
      for (int r = 0; r < 4; r++)
        Ps[w][1][(quad * 4 + r) * 68 + g * 16 + l16] = truncbf(EXP2(svB[g][r]));

#pragma unroll
    for (int kf = 0; kf < 2; kf++) {
      short8 vb[4];
#pragma unroll
      for (int g2 = 0; g2 < 4; g2++)
        vb[g2] = *(const short8*)&Vs[(g2 * 16 + l16) * 68 + kf * 32 + quad * 8];
      short8 paB = *(const short8*)&Ps[w][1][l16 * 68 + kf * 32 + quad * 8];
      acclB = __builtin_amdgcn_mfma_f32_16x16x32_bf16(paB, ones, acclB, 0, 0, 0);
#pragma unroll
      for (int g2 = 0; g2 < 4; g2++)
        accyB[g2] = __builtin_amdgcn_mfma_f32_16x16x32_bf16(paB, vb[g2], accyB[g2], 0, 0, 0);
      if (doA) {
        short8 paA = *(const short8*)&Ps[w][0][l16 * 68 + kf * 32 + quad * 8];
        acclA = __builtin_amdgcn_mfma_f32_16x16x32_bf16(paA, ones, acclA, 0, 0, 0);
#pragma unroll
        for (int g2 = 0; g2 < 4; g2++)
          accyA[g2] = __builtin_amdgcn_mfma_f32_16x16x32_bf16(paA, vb[g2], accyA[g2], 0, 0, 0);
      }
    }
  }

  float invA[4], invB[4];
#pragma unroll
  for (int r = 0; r < 4; r++) {
    invA[r] = 1.0f / acclA[r];
    invB[r] = 1.0f / acclB[r];
  }
#pragma unroll
  for (int g2 = 0; g2 < 4; g2++) {
    int col = h * HEAD_DIM + g2 * 16 + l16;
#pragma unroll
    for (int r = 0; r < 4; r++) {
      int giA = iA + quad * 4 + r;
      int giB = iB + quad * 4 + r;
      Y[(rowb + giA) * N_EMBD + col] = f2bf(accyA[g2][r] * invA[r]);
      Y[(rowb + giB) * N_EMBD + col] = f2bf(accyB[g2][r] * invB[r]);
    }
  }
}

// ---------------------------------------------------------------------------
extern "C" void kernel_launch(void* const* d_in, const int* in_sizes, int n_in,
                              void* d_out, int out_size, void* d_ws, size_t ws_size,
                              hipStream_t stream) {
  (void)in_sizes; (void)n_in; (void)out_size; (void)ws_size;
  const void* x   = d_in[0];
  const void* Wsh = d_in[1];
  const void* bsh = d_in[2];
  const void* Wq  = d_in[3];
  const void* bq  = d_in[4];
  const void* Wk  = d_in[5];
  const void* bk  = d_in[6];
  const void* Wv  = d_in[7];
  const void* bv  = d_in[8];
  const void* Wo  = d_in[9];
  const void* bo  = d_in[10];

  char* wsb = (char*)d_ws;
  int* flag = (int*)wsb;
  u16* ws16 = (u16*)(wsb + 64);
  u16* Wcat = ws16;                                   // PNS*1024 (transposed)
  u16* bcat = Wcat + (size_t)PNS * N_EMBD;            // PNS
  u16* Woc  = bcat + PNS;                             // 1024*1024 (transposed)
  u16* boc  = Woc + (size_t)N_EMBD * N_EMBD;          // 1024
  u16* Pb   = boc + N_EMBD;                           // 8192*2688
  u16* Yb   = Pb + (size_t)M_ROWS * PNS;              // 8192*1024

  detect_kernel<<<dim3(1), dim3(256), 0, stream>>>((const u16*)x, flag);
  pack_t_kernel<<<dim3(16, 16, 5), dim3(256), 0, stream>>>(
      Wsh, Wq, Wk, Wv, Wo, Wcat, Woc, flag);
  pad_bias_kernel<<<dim3(64), dim3(256), 0, stream>>>(
      bsh, bq, bk, bv, bo, Wcat, bcat, boc, flag);
  // proj GEMM: both dtype variants launched; wrong one exits on the flag
  gemm_bias_kernel<false><<<dim3(64 * (PNS / 128)), dim3(256), 0, stream>>>(
      x, N_EMBD, Wcat, bcat, Pb, PNS, N_EMBD, flag, 1, 0);
  gemm_bias_kernel<true><<<dim3(64 * (PNS / 128)), dim3(256), 0, stream>>>(
      x, N_EMBD, Wcat, bcat, Pb, PNS, N_EMBD, flag, 1, 0);
  attn_kernel<<<dim3(BATCH * N_HEADS, NTILES / 2), dim3(256), 0, stream>>>(
      Pb, Yb);
  // out GEMM: A (Yb) is always bf16
  gemm_bias_kernel<false><<<dim3(64 * (N_EMBD / 128)), dim3(256), 0, stream>>>(
      Yb, N_EMBD, Woc, boc, d_out, N_EMBD, N_EMBD, flag, 0, 1);
}

// Round 7
// 309.252 us; speedup vs baseline: 1.5744x; 1.5744x over previous
//
#include <hip/hip_runtime.h>
#include <hip/hip_bf16.h>

typedef unsigned short u16;
typedef short short8 __attribute__((ext_vector_type(8)));
typedef float f32x4 __attribute__((ext_vector_type(4)));

#define N_EMBD   1024
#define N_HEADS  16
#define HEAD_DIM 64
#define PRIV     48
#define SEQ_T    2048
#define BATCH    4
#define M_ROWS   (BATCH*SEQ_T)   // 8192
#define PNS      2688            // [share 16 | q 768 | k 768 | v 1024] = 2576 -> 21*128
#define NTILES   (SEQ_T/64)      // 32

#if __has_builtin(__builtin_amdgcn_exp2f)
#define EXP2(x) __builtin_amdgcn_exp2f(x)
#else
#define EXP2(x) exp2f(x)
#endif

#if __has_builtin(__builtin_amdgcn_global_load_lds)
#define HAVE_GLL 1
#else
#define HAVE_GLL 0
#endif

__device__ __forceinline__ u16 f2bf(float f) {
  __hip_bfloat16 h = __float2bfloat16(f);
  return *reinterpret_cast<u16*>(&h);
}
__device__ __forceinline__ float bf2f(u16 s) {
  __hip_bfloat16 h;
  *reinterpret_cast<u16*>(&h) = s;
  return __bfloat162float(h);
}
__device__ __forceinline__ float loadv(const void* p, size_t i, int isf32) {
  return isf32 ? ((const float*)p)[i] : bf2f(((const u16*)p)[i]);
}
__device__ __forceinline__ u16 truncbf(float f) {
  unsigned u = __builtin_bit_cast(unsigned, f);
  return (u16)(u >> 16);
}
#if HAVE_GLL
__device__ __forceinline__ void gload_lds16(const u16* g, u16* l) {
  __builtin_amdgcn_global_load_lds(
      (const __attribute__((address_space(1))) void*)g,
      (__attribute__((address_space(3))) void*)l, 16, 0, 0);
}
#endif

// ---------------------------------------------------------------------------
// Dtype detector (1 = f32 inputs).
// ---------------------------------------------------------------------------
__global__ __launch_bounds__(256) void detect_kernel(const u16* __restrict__ x,
                                                     int* __restrict__ flag) {
  __shared__ int cnt;
  if (threadIdx.x == 0) cnt = 0;
  __syncthreads();
  u16 v = x[2 * threadIdx.x];
  int e = (v >> 7) & 0xFF;
  int junk = (e >= 0xC0 || (e != 0 && e <= 0x30)) ? 1 : 0;
  if (junk) atomicAdd(&cnt, 1);
  __syncthreads();
  if (threadIdx.x == 0) *flag = (cnt > 16) ? 1 : 0;
}

// ---------------------------------------------------------------------------
// Transposing pack (weights -> [n][k] bf16) + z=5 slice does zero-pad + biases.
// ---------------------------------------------------------------------------
__global__ __launch_bounds__(256) void pack_t_kernel(
    const void* __restrict__ Wsh, const void* __restrict__ Wq,
    const void* __restrict__ Wk,  const void* __restrict__ Wv,
    const void* __restrict__ Wo,
    const void* __restrict__ bsh, const void* __restrict__ bq,
    const void* __restrict__ bk,  const void* __restrict__ bv,
    const void* __restrict__ bo,
    u16* __restrict__ Wcat, u16* __restrict__ Woc,
    u16* __restrict__ bcat, u16* __restrict__ boc,
    const int* __restrict__ flagp)
{
  const int f = *flagp;
  if (blockIdx.z == 5) {  // pad + biases
    const int flat = blockIdx.y * 16 + blockIdx.x;
    const int padN = (PNS - 2576) * 1024;
    for (int i = flat * 256 + threadIdx.x; i < padN; i += 256 * 256)
      Wcat[(size_t)2576 * 1024 + i] = 0;
    if (flat == 0) {
      for (int c = threadIdx.x; c < PNS; c += 256) {
        float v = 0.f;
        if (c < 16)        v = loadv(bsh, c, f);
        else if (c < 784)  v = loadv(bq, c - 16, f);
        else if (c < 1552) v = loadv(bk, c - 784, f);
        else if (c < 2576) v = loadv(bv, c - 1552, f);
        bcat[c] = f2bf(v);
      }
    } else if (flat == 1) {
      for (int c = threadIdx.x; c < N_EMBD; c += 256)
        boc[c] = f2bf(loadv(bo, c, f));
    }
    return;
  }
  const void* src; u16* dst; int N, rowOff;
  switch (blockIdx.z) {
    case 0: src = Wsh; dst = Wcat; N = 16;   rowOff = 0;    break;
    case 1: src = Wq;  dst = Wcat; N = 768;  rowOff = 16;   break;
    case 2: src = Wk;  dst = Wcat; N = 768;  rowOff = 784;  break;
    case 3: src = Wv;  dst = Wcat; N = 1024; rowOff = 1552; break;
    default:src = Wo;  dst = Woc;  N = 1024; rowOff = 0;    break;
  }
  const int n0 = blockIdx.x * 64;
  if (n0 >= N) return;
  const int k0 = blockIdx.y * 64;
  __shared__ u16 t[64][65];
  const int tx = threadIdx.x & 63, ty = threadIdx.x >> 6;
#pragma unroll
  for (int rr = 0; rr < 16; rr++) {
    int k = k0 + ty * 16 + rr;
    int n = n0 + tx;
    float v = (n < N) ? loadv(src, (size_t)k * N + n, f) : 0.f;
    t[ty * 16 + rr][tx] = f2bf(v);
  }
  __syncthreads();
#pragma unroll
  for (int rr = 0; rr < 16; rr++) {
    int n = ty * 16 + rr;
    if (n0 + n < N)
      dst[(size_t)(rowOff + n0 + n) * 1024 + k0 + tx] = t[tx][n];
  }
}

// ---------------------------------------------------------------------------
// V transpose: Vt[(b*16+h)*64 + d][t] = P[b*T+t][vcol(h)+d]. 64x64 LDS tiles.
// grid (T/64, B*H), 256 thr.
// ---------------------------------------------------------------------------
__global__ __launch_bounds__(256) void vt_kernel(const u16* __restrict__ P,
                                                 u16* __restrict__ Vt)
{
  const int tt = blockIdx.x * 64;
  const int bh = blockIdx.y;
  const int b = bh >> 4, h = bh & 15;
  const int vcol = 1552 + h * HEAD_DIM;
  __shared__ u16 t[64][65];
  const int tx = threadIdx.x & 63, ty = threadIdx.x >> 6;
#pragma unroll
  for (int rr = 0; rr < 16; rr++) {
    int r = ty * 16 + rr;
    t[r][tx] = P[((size_t)b * SEQ_T + tt + r) * PNS + vcol + tx];
  }
  __syncthreads();
#pragma unroll
  for (int rr = 0; rr < 16; rr++) {
    int d = ty * 16 + rr;
    Vt[((size_t)bh * 64 + d) * SEQ_T + tt + tx] = t[tx][d];
  }
}

// ---------------------------------------------------------------------------
// BF16 GEMM, LDS double-buffered global_load_lds prefetch pipeline.
// C(MxN) = A(MxK) @ Bt(NxK)^T + bias. 128x128 tile, BK=32, 256 thr.
// Per iter: DMA tile k+1 into buf[1-cur] (no wait), frag-read + 16 MFMAs on
// buf[cur], ONE barrier (its vmcnt(0) drain overlaps the whole compute phase).
// No VGPR prefetch -> no spill (R6 lesson). XOR chunk swizzle folded into the
// GLOBAL address; frag ds_read_b128 conflict <=2-way (free).
// XCD-aware 1-D grid swizzle (requires M = 8192).
// ---------------------------------------------------------------------------
template <bool AF32>
__global__ __launch_bounds__(256, 3) void gemm_bias_kernel(
    const void* __restrict__ A, int lda,
    const u16* __restrict__ Bt,     // [N][K] row-major
    const u16* __restrict__ bias,
    void* __restrict__ C, int ldc, int K,
    const int* __restrict__ flagp, int a_dyn, int c_dyn)
{
  const int isf = *flagp;
  if (AF32 != (a_dyn != 0 && isf != 0)) return;   // uniform exit, wrong variant
  const bool cf32 = (c_dyn != 0) && (isf != 0);

  __shared__ __align__(16) u16 As[2][128 * 32];
  __shared__ __align__(16) u16 Bs[2][128 * 32];
  const int tid  = threadIdx.x;
  const int lane = tid & 63;
  const int w    = tid >> 6;
  const int quad = lane >> 4;
  const int l16  = lane & 15;

  // XCD-aware block swizzle (bid -> XCD assumed bid % 8)
  const int bid = blockIdx.x;
  const int xcd = bid & 7;
  const int s   = bid >> 3;
  const int mb  = xcd * 8 + (s & 7);
  const int nb  = s >> 3;
  const int m0  = mb * 128;
  const int n0  = nb * 128;
  const int wm  = (w >> 1) * 64;
  const int wn  = (w & 1) * 64;

  // staging geometry: round i covers chunk index c = tid + i*256
  // LDS slot is lane-linear (c*8); GLOBAL chunk is XOR-swizzled
  int mS[2], lgS[2];
#pragma unroll
  for (int i = 0; i < 2; i++) {
    int c  = tid + i * 256;
    int m  = c >> 2;
    int pc = c & 3;
    mS[i]  = m;
    lgS[i] = (pc ^ (m & 3) ^ ((m >> 2) & 3)) * 8;
  }

  const u16* A16  = (const u16*)A;
  const float* A32 = (const float*)A;

#define STAGE(k0, bb)                                                          \
  {                                                                            \
    _Pragma("unroll") for (int i = 0; i < 2; i++) {                            \
      int c = tid + i * 256;                                                   \
      if (AF32) {                                                              \
        const float* srcp = A32 + (size_t)(m0 + mS[i]) * lda + (k0) + lgS[i];  \
        float4 v0 = *(const float4*)srcp;                                      \
        float4 v1 = *(const float4*)(srcp + 4);                                \
        u16 tb[8];                                                             \
        tb[0] = f2bf(v0.x); tb[1] = f2bf(v0.y); tb[2] = f2bf(v0.z);            \
        tb[3] = f2bf(v0.w); tb[4] = f2bf(v1.x); tb[5] = f2bf(v1.y);            \
        tb[6] = f2bf(v1.z); tb[7] = f2bf(v1.w);                                \
        *(uint4*)&As[bb][c * 8] = *(const uint4*)tb;                           \
        *(uint4*)&Bs[bb][c * 8] =                                              \
            *(const uint4*)(Bt + (size_t)(n0 + mS[i]) * K + (k0) + lgS[i]);    \
      } else {                                                                 \
        GLOAD(A16 + (size_t)(m0 + mS[i]) * lda + (k0) + lgS[i], &As[bb][c*8]); \
        GLOAD(Bt + (size_t)(n0 + mS[i]) * K + (k0) + lgS[i], &Bs[bb][c*8]);    \
      }                                                                        \
    }                                                                          \
  }
#if HAVE_GLL
#define GLOAD(g, l) gload_lds16((g), (l))
#else
#define GLOAD(g, l) (*(uint4*)(l) = *(const uint4*)(g))
#endif

  f32x4 acc[4][4];
#pragma unroll
  for (int i = 0; i < 4; i++)
#pragma unroll
    for (int j = 0; j < 4; j++) acc[i][j] = (f32x4){0.f, 0.f, 0.f, 0.f};

  const int swr = (quad ^ (l16 & 3) ^ ((l16 >> 2) & 3)) * 8;

  STAGE(0, 0);
  __syncthreads();

  const int NIT = K / 32;
  for (int kt = 0; kt < NIT; kt++) {
    const int cur = kt & 1;
    if (kt + 1 < NIT) STAGE((kt + 1) * 32, 1 - cur);   // prefetch, no wait

    short8 af[4], bfr[4];
#pragma unroll
    for (int mt = 0; mt < 4; mt++)
      af[mt] = *(const short8*)&As[cur][(wm + mt * 16 + l16) * 32 + swr];
#pragma unroll
    for (int nt = 0; nt < 4; nt++)
      bfr[nt] = *(const short8*)&Bs[cur][(wn + nt * 16 + l16) * 32 + swr];
#pragma unroll
    for (int mt = 0; mt < 4; mt++)
#pragma unroll
      for (int nt = 0; nt < 4; nt++)
        acc[mt][nt] = __builtin_amdgcn_mfma_f32_16x16x32_bf16(af[mt], bfr[nt], acc[mt][nt], 0, 0, 0);

    if (kt + 1 < NIT) __syncthreads();  // drains overlapped prefetch
  }
#undef STAGE
#undef GLOAD

  // ---- epilogue: C/D layout col=lane&15, row=quad*4+reg ----
#pragma unroll
  for (int nt = 0; nt < 4; nt++) {
    int col  = n0 + wn + nt * 16 + l16;
    float bv = bf2f(bias[col]);
#pragma unroll
    for (int mt = 0; mt < 4; mt++) {
#pragma unroll
      for (int r = 0; r < 4; r++) {
        int row   = m0 + wm + mt * 16 + quad * 4 + r;
        float val = acc[mt][nt][r] + bv;
        if (cf32) ((float*)C)[(size_t)row * ldc + col] = val;
        else      ((u16*)C)[(size_t)row * ldc + col]   = f2bf(val);
      }
    }
  }
}

// ---------------------------------------------------------------------------
// Causal flash attention, balanced-pair + K/V LDS double-buffer prefetch.
// Block = (b,h, pair p): q-tiles qtA=p, qtB=31-p -> 33 k-tiles per block.
// K staged from P (column-gathered), V staged from compact pre-transposed Vt;
// both via global_load_lds with XOR swizzle, prefetched one tile ahead.
// Fixed-max softmax; rowsum via ones-column MFMA; Ps per-wave (no barrier).
// ---------------------------------------------------------------------------
__global__ __launch_bounds__(256, 3) void attn_kernel(
    const u16* __restrict__ P, const u16* __restrict__ Vt,
    u16* __restrict__ Y)
{
  const int bh  = blockIdx.x;
  const int b   = bh >> 4, h = bh & 15;
  const int p   = blockIdx.y;           // 0..15
  const int qtA = p, qtB = NTILES - 1 - p;
  const int tid = threadIdx.x;
  const int w   = tid >> 6;
  const int lane = tid & 63;
  const int quad = lane >> 4, l16 = lane & 15;
  const size_t rowb = (size_t)b * SEQ_T;
  const int qcol = 16 + h * PRIV;
  const int kcol = 784 + h * PRIV;

  __shared__ __align__(16) u16 Ks[2][64 * 64];     // [j][chunk^(j&7)]
  __shared__ __align__(16) u16 Vs[2][64 * 64];     // [d][tchunk^(d&7)]
  __shared__ __align__(16) u16 Ps[4][2][16 * 68];  // [wave][chain]

  const float csc = 0.18033688011112042f;  // (1/8)*log2(e)
  const int d0  = quad * 8;
  const int cq0 = (d0 < 16) ? d0 : (qcol + d0 - 16);
  const int iA = qtA * 64 + w * 16, iB = qtB * 64 + w * 16;
  const u16* qrowA = P + (rowb + iA + l16) * PNS;
  const u16* qrowB = P + (rowb + iB + l16) * PNS;
  short8 qaA0 = *(const short8*)&qrowA[cq0];
  short8 qaA1 = *(const short8*)&qrowA[qcol + 16 + d0];
  short8 qaB0 = *(const short8*)&qrowB[cq0];
  short8 qaB1 = *(const short8*)&qrowB[qcol + 16 + d0];
#pragma unroll
  for (int e = 0; e < 8; e++) {
    qaA0[e] = (short)f2bf(bf2f((u16)qaA0[e]) * csc);
    qaA1[e] = (short)f2bf(bf2f((u16)qaA1[e]) * csc);
    qaB0[e] = (short)f2bf(bf2f((u16)qaB0[e]) * csc);
    qaB1[e] = (short)f2bf(bf2f((u16)qaB1[e]) * csc);
  }
  short8 ones;
#pragma unroll
  for (int e = 0; e < 8; e++) ones[e] = (short)0x3F80;

  // staging geometry (shared by K and V): c = tid + i2*256
  // row = c>>3 (j for K, d for V), phys chunk pc = c&7, logical = pc ^ (row&7)
#if HAVE_GLL
#define GLOADA(g, l) gload_lds16((g), (l))
#else
#define GLOADA(g, l) (*(uint4*)(l) = *(const uint4*)(g))
#endif
#define STAGE_KV(k0, bb)                                                       \
  {                                                                            \
    _Pragma("unroll") for (int i2 = 0; i2 < 2; i2++) {                         \
      int c   = tid + i2 * 256;                                                \
      int row = c >> 3;                                                        \
      int dg  = ((c & 7) ^ (row & 7)) * 8;                                     \
      int col = (dg < 16) ? dg : (kcol + dg - 16);                             \
      GLOADA(&P[(rowb + (k0) + row) * PNS + col], &Ks[bb][c * 8]);             \
      GLOADA(&Vt[((size_t)bh * 64 + row) * SEQ_T + (k0) + dg], &Vs[bb][c * 8]);\
    }                                                                          \
  }

  f32x4 accyA[4], accyB[4], acclA, acclB;
#pragma unroll
  for (int g = 0; g < 4; g++) {
    accyA[g] = (f32x4){0.f, 0.f, 0.f, 0.f};
    accyB[g] = (f32x4){0.f, 0.f, 0.f, 0.f};
  }
  acclA = (f32x4){0.f, 0.f, 0.f, 0.f};
  acclB = (f32x4){0.f, 0.f, 0.f, 0.f};

  const int nkt = qtB + 1;
  STAGE_KV(0, 0);
  __syncthreads();

  for (int kt = 0; kt < nkt; kt++) {
    const int cur = kt & 1;
    const int k0  = kt * 64;
    if (kt + 1 < nkt) STAGE_KV((kt + 1) * 64, 1 - cur);  // prefetch, no wait

    const bool doA = (kt <= qtA);

    // ---- S = Qs K^T for both chains (K frags from LDS, shared) ----
    float svA[4][4], svB[4][4];
#pragma unroll
    for (int g = 0; g < 4; g++) {
      int j = g * 16 + l16;
      short8 kb0 = *(const short8*)&Ks[cur][j * 64 + ((quad    ) ^ (j & 7)) * 8];
      short8 kb1 = *(const short8*)&Ks[cur][j * 64 + ((quad + 4) ^ (j & 7)) * 8];
      f32x4 sB = (f32x4){0.f, 0.f, 0.f, 0.f};
      sB = __builtin_amdgcn_mfma_f32_16x16x32_bf16(qaB0, kb0, sB, 0, 0, 0);
      sB = __builtin_amdgcn_mfma_f32_16x16x32_bf16(qaB1, kb1, sB, 0, 0, 0);
#pragma unroll
      for (int r = 0; r < 4; r++) svB[g][r] = sB[r];
      if (doA) {
        f32x4 sA = (f32x4){0.f, 0.f, 0.f, 0.f};
        sA = __builtin_amdgcn_mfma_f32_16x16x32_bf16(qaA0, kb0, sA, 0, 0, 0);
        sA = __builtin_amdgcn_mfma_f32_16x16x32_bf16(qaA1, kb1, sA, 0, 0, 0);
#pragma unroll
        for (int r = 0; r < 4; r++) svA[g][r] = sA[r];
      }
    }
    if (kt == qtA && doA) {
#pragma unroll
      for (int g = 0; g < 4; g++)
#pragma unroll
        for (int r = 0; r < 4; r++) {
          int gi = iA + quad * 4 + r;
          int gj = k0 + g * 16 + l16;
          if (gj > gi) svA[g][r] = -__builtin_inff();
        }
    }
    if (kt == qtB) {
#pragma unroll
      for (int g = 0; g < 4; g++)
#pragma unroll
        for (int r = 0; r < 4; r++) {
          int gi = iB + quad * 4 + r;
          int gj = k0 + g * 16 + l16;
          if (gj > gi) svB[g][r] = -__builtin_inff();
        }
    }

    // ---- p = exp2(s) -> bf16 -> per-wave LDS (C->A layout) ----
    if (doA) {
#pragma unroll
      for (int g = 0; g < 4; g++)
#pragma unroll
        for (int r = 0; r < 4; r++)
          Ps[w][0][(quad * 4 + r) * 68 + g * 16 + l16] = truncbf(EXP2(svA[g][r]));
    }
#pragma unroll
    for (int g = 0; g < 4; g++)
#pragma unroll
      for (int r = 0; r < 4; r++)
        Ps[w][1][(quad * 4 + r) * 68 + g * 16 + l16] = truncbf(EXP2(svB[g][r]));

    // ---- y += P@V ; l += P@ones  (V frags shared across chains) ----
#pragma unroll
    for (int kf = 0; kf < 2; kf++) {
      short8 vb[4];
#pragma unroll
      for (int g2 = 0; g2 < 4; g2++) {
        int row = g2 * 16 + l16;
        vb[g2] = *(const short8*)&Vs[cur][row * 64 + (((kf * 4 + quad) ^ (row & 7)) * 8)];
      }
      short8 paB = *(const short8*)&Ps[w][1][l16 * 68 + kf * 32 + quad * 8];
      acclB = __builtin_amdgcn_mfma_f32_16x16x32_bf16(paB, ones, acclB, 0, 0, 0);
#pragma unroll
      for (int g2 = 0; g2 < 4; g2++)
        accyB[g2] = __builtin_amdgcn_mfma_f32_16x16x32_bf16(paB, vb[g2], accyB[g2], 0, 0, 0);
      if (doA) {
        short8 paA = *(const short8*)&Ps[w][0][l16 * 68 + kf * 32 + quad * 8];
        acclA = __builtin_amdgcn_mfma_f32_16x16x32_bf16(paA, ones, acclA, 0, 0, 0);
#pragma unroll
        for (int g2 = 0; g2 < 4; g2++)
          accyA[g2] = __builtin_amdgcn_mfma_f32_16x16x32_bf16(paA, vb[g2], accyA[g2], 0, 0, 0);
      }
    }

    if (kt + 1 < nkt) __syncthreads();  // drains overlapped prefetch
  }
#undef STAGE_KV
#undef GLOADA

  float invA[4], invB[4];
#pragma unroll
  for (int r = 0; r < 4; r++) {
    invA[r] = 1.0f / acclA[r];
    invB[r] = 1.0f / acclB[r];
  }
#pragma unroll
  for (int g2 = 0; g2 < 4; g2++) {
    int col = h * HEAD_DIM + g2 * 16 + l16;
#pragma unroll
    for (int r = 0; r < 4; r++) {
      int giA = iA + quad * 4 + r;
      int giB = iB + quad * 4 + r;
      Y[(rowb + giA) * N_EMBD + col] = f2bf(accyA[g2][r] * invA[r]);
      Y[(rowb + giB) * N_EMBD + col] = f2bf(accyB[g2][r] * invB[r]);
    }
  }
}

// ---------------------------------------------------------------------------
extern "C" void kernel_launch(void* const* d_in, const int* in_sizes, int n_in,
                              void* d_out, int out_size, void* d_ws, size_t ws_size,
                              hipStream_t stream) {
  (void)in_sizes; (void)n_in; (void)out_size; (void)ws_size;
  const void* x   = d_in[0];
  const void* Wsh = d_in[1];
  const void* bsh = d_in[2];
  const void* Wq  = d_in[3];
  const void* bq  = d_in[4];
  const void* Wk  = d_in[5];
  const void* bk  = d_in[6];
  const void* Wv  = d_in[7];
  const void* bv  = d_in[8];
  const void* Wo  = d_in[9];
  const void* bo  = d_in[10];

  char* wsb = (char*)d_ws;
  int* flag = (int*)wsb;
  u16* ws16 = (u16*)(wsb + 64);
  u16* Wcat = ws16;                                   // PNS*1024 (transposed)
  u16* bcat = Wcat + (size_t)PNS * N_EMBD;            // PNS
  u16* Woc  = bcat + PNS;                             // 1024*1024 (transposed)
  u16* boc  = Woc + (size_t)N_EMBD * N_EMBD;          // 1024
  u16* Pb   = boc + N_EMBD;                           // 8192*2688
  u16* Yb   = Pb + (size_t)M_ROWS * PNS;              // 8192*1024
  u16* Vtb  = Yb + (size_t)M_ROWS * N_EMBD;           // 64*64*2048 = 8.4 MB

  detect_kernel<<<dim3(1), dim3(256), 0, stream>>>((const u16*)x, flag);
  pack_t_kernel<<<dim3(16, 16, 6), dim3(256), 0, stream>>>(
      Wsh, Wq, Wk, Wv, Wo, bsh, bq, bk, bv, bo, Wcat, Woc, bcat, boc, flag);
  // proj GEMM: both dtype variants launched; wrong one exits on the flag
  gemm_bias_kernel<false><<<dim3(64 * (PNS / 128)), dim3(256), 0, stream>>>(
      x, N_EMBD, Wcat, bcat, Pb, PNS, N_EMBD, flag, 1, 0);
  gemm_bias_kernel<true><<<dim3(64 * (PNS / 128)), dim3(256), 0, stream>>>(
      x, N_EMBD, Wcat, bcat, Pb, PNS, N_EMBD, flag, 1, 0);
  vt_kernel<<<dim3(SEQ_T / 64, BATCH * N_HEADS), dim3(256), 0, stream>>>(
      Pb, Vtb);
  attn_kernel<<<dim3(BATCH * N_HEADS, NTILES / 2), dim3(256), 0, stream>>>(
      Pb, Vtb, Yb);
  // out GEMM: A (Yb) is always bf16
  gemm_bias_kernel<false><<<dim3(64 * (N_EMBD / 128)), dim3(256), 0, stream>>>(
      Yb, N_EMBD, Woc, boc, d_out, N_EMBD, N_EMBD, flag, 0, 1);
}